// Round 2
// baseline (198.164 us; speedup 1.0000x reference)
//
#include <hip/hip_runtime.h>

#define NN 4096
#define DD 128
#define HH1 256

// ---------------- new-path workspace float offsets ----------------
#define WS_S    0        // 16384 : S = (weight*A)^2 / 128
#define WS_S2   16384    // 16384
#define WS_S3   32768    // 16384
#define WS_S4   49152    // 16384
#define WS_W    65536    // 16384 : W = weight*A
#define WS_W2S  81920    // 256
#define WS_PAIR 82176    // 512   : float2 {b1[j], w2s[j]}
#define WS_B2S  82688    // 1
#define WS_TACC 82696    // 10
#define WS_DONE 82708    // 1 (uint)
#define WS_REGP 82712    // 8
#define WS_BAR  82720    // 4 uints (grid barrier slots, zeroed by memset)
#define WS_WT   82944    // 16384 : WT[i][k] = W[k][i]
#define WS_XT   99328    // 524288 : xT[128][4096]
#define WS_REQ_FLOATS 623616
#define WS_REQ_BYTES  (WS_REQ_FLOATS * 4UL)

// ---------------- old-path (fallback) offsets ----------------
#define O_S    0
#define O_S2   16384
#define O_S3   32768
#define O_S4   49152
#define O_W2S  65536
#define O_B2S  65792
#define O_TACC 65808
#define O_DONE 65824
#define O_REGP 65840

__device__ __forceinline__ float waveReduce(float v) {
#pragma unroll
  for (int off = 32; off > 0; off >>= 1) v += __shfl_down(v, off, 64);
  return v;
}

// Grid-wide barrier: single-use counter per phase boundary.
// Release: __threadfence before arrive; acquire: agent-scope atomic load.
// Safe: grid=256 blocks @ 68KB LDS/512thr -> all co-resident on 256 CUs.
__device__ __forceinline__ void gridBarrier(unsigned int* bar,
                                            unsigned int nblk) {
  __syncthreads();
  if (threadIdx.x == 0) {
    __threadfence();
    __hip_atomic_fetch_add(bar, 1u, __ATOMIC_ACQ_REL,
                           __HIP_MEMORY_SCOPE_AGENT);
    unsigned int v = __hip_atomic_load(bar, __ATOMIC_ACQUIRE,
                                       __HIP_MEMORY_SCOPE_AGENT);
    while (v < nblk) {
      __builtin_amdgcn_s_sleep(2);
      v = __hip_atomic_load(bar, __ATOMIC_ACQUIRE,
                            __HIP_MEMORY_SCOPE_AGENT);
    }
  }
  __syncthreads();
}

// =====================================================================
// NEW PATH: single persistent kernel, 256 blocks x 512 threads
// =====================================================================
__global__ __launch_bounds__(512) void kFused(
    const float* __restrict__ x, const float* __restrict__ weight,
    const float* __restrict__ Amat, const float* __restrict__ bias,
    const float* __restrict__ W1, const float* __restrict__ b1v,
    const float* __restrict__ W2, const float* __restrict__ b2,
    float* __restrict__ ws, float* __restrict__ out) {
  __shared__ float smem[17024];  // 68 KB, aliased per phase
  const int b = blockIdx.x, tid = threadIdx.x;
  unsigned int* bar = (unsigned int*)(ws + WS_BAR);

  // ================= phase 0 =================
  if (b < 32) {
    // S2 = S @ S with S = (weight*A)^2/128 staged in LDS (4 rows/block)
    const float4* w4 = (const float4*)weight;
    const float4* a4 = (const float4*)Amat;
    float4* s4 = (float4*)smem;
    const float inv = 1.0f / 128.0f;
    for (int e = tid; e < DD * DD / 4; e += 512) {
      float4 wv = w4[e], av = a4[e], o;
      float t;
      t = wv.x * av.x; o.x = t * t * inv;
      t = wv.y * av.y; o.y = t * t * inv;
      t = wv.z * av.z; o.z = t * t * inv;
      t = wv.w * av.w; o.w = t * t * inv;
      s4[e] = o;
    }
    __syncthreads();
    const int i = (b << 2) + (tid >> 7), j = tid & 127;
    const float* row = &smem[i * DD];
    float acc = 0.f;
#pragma unroll 8
    for (int k = 0; k < DD; ++k) acc = fmaf(row[k], smem[k * DD + j], acc);
    ws[WS_S2 + i * DD + j] = acc;
  } else if (b < 40) {
    // W, WT, S global write
    const int base = (b - 32) * 2048;
    const float inv = 1.0f / 128.0f;
    for (int e = tid; e < 2048; e += 512) {
      const int idx = base + e;
      const float w = weight[idx] * Amat[idx];
      const int k = idx >> 7, i = idx & 127;
      ws[WS_W + idx] = w;
      ws[WS_WT + i * DD + k] = w;
      ws[WS_S + idx] = w * w * inv;
    }
  } else if (b == 40) {
    if (tid < 256) {
      const float4* r = (const float4*)(W2 + tid * 128);
      float4 s4 = make_float4(0.f, 0.f, 0.f, 0.f);
#pragma unroll 8
      for (int k = 0; k < 32; ++k) {
        const float4 v = r[k];
        s4.x += v.x; s4.y += v.y; s4.z += v.z; s4.w += v.w;
      }
      const float w2sv = (s4.x + s4.y) + (s4.z + s4.w);
      ws[WS_W2S + tid] = w2sv;
      ((float2*)(ws + WS_PAIR))[tid] = make_float2(b1v[tid], w2sv);
    }
  } else if (b == 41) {
    float v = (tid < 128) ? b2[tid] : 0.f;
    v = waveReduce(v);
    float* red = smem;
    if ((tid & 63) == 0) red[tid >> 6] = v;
    __syncthreads();
    if (tid == 0) {
      float s = 0.f;
      for (int m = 0; m < 8; ++m) s += red[m];
      ws[WS_B2S] = s;
    }
    if (tid >= 64 && tid < 74) ws[WS_TACC + (tid - 64)] = 0.f;
    if (tid == 96) *(unsigned int*)(ws + WS_DONE) = 0u;
  } else if (b < 50) {
    // l1 reg partials
    const int bb = b - 42;
    const int base = bb * 2048;
    float s = 0.f;
    for (int e = tid; e < 2048; e += 512) {
      const int idx = base + e;
      s += fabsf(weight[idx] * Amat[idx]);
    }
    s = waveReduce(s);
    float* red2 = smem;
    if ((tid & 63) == 0) red2[tid >> 6] = s;
    __syncthreads();
    if (tid == 0) {
      float t = 0.f;
      for (int m = 0; m < 8; ++m) t += red2[m];
      ws[WS_REGP + bb] = t;
    }
  } else if (b < 82) {
    // xT transpose: 32 tiles of 128 rows
    const int n0 = (b - 50) * 128;
    const float4* x4 = (const float4*)x;
    for (int e = tid; e < 4096; e += 512) {
      const int r = e >> 5, c = e & 31;
      const float4 v = x4[(n0 + r) * 32 + c];
      float* p = &smem[r * 133 + (c << 2)];
      p[0] = v.x; p[1] = v.y; p[2] = v.z; p[3] = v.w;
    }
    __syncthreads();
    float* xT = ws + WS_XT;
    const int c = tid & 31, ks = tid >> 5;  // ks: 0..15
#pragma unroll
    for (int m = 0; m < 8; ++m) {
      const int k = ks + (m << 4);
      float4 o;
      o.x = smem[((c << 2) + 0) * 133 + k];
      o.y = smem[((c << 2) + 1) * 133 + k];
      o.z = smem[((c << 2) + 2) * 133 + k];
      o.w = smem[((c << 2) + 3) * 133 + k];
      *(float4*)&xT[k * NN + n0 + (c << 2)] = o;
    }
  }

  gridBarrier(bar, 256);

  // ================= phase 1: fused y+f tile (all 256 blocks) ==========
  {
    const int fb = b;
    const int n0 = (fb & 15) << 8, i0 = (fb >> 4) << 3;
    const int w = tid >> 6, l = tid & 63;
    float* xs = smem;          // [32][256] = 8192 floats
    float* ts = smem + 8192;   // [256][9]  = 2304 floats
    const float* __restrict__ xT = ws + WS_XT;
    const float* __restrict__ WTm = ws + WS_WT;
    const int iu = __builtin_amdgcn_readfirstlane(i0 + w);  // force SGPR

    float t[4] = {0.f, 0.f, 0.f, 0.f};
    for (int kc = 0; kc < 4; ++kc) {
      __syncthreads();
      {
        const float4* src = (const float4*)(xT + (kc * 32) * NN + n0);
        float4* dst4 = (float4*)xs;
#pragma unroll
        for (int m = 0; m < 4; ++m) {
          const int e = tid + (m << 9);  // 0..2047
          const int kk = e >> 6, c = e & 63;
          dst4[(kk << 6) + c] = src[kk * (NN / 4) + c];
        }
      }
      __syncthreads();
      const float* wr = WTm + iu * DD + kc * 32;  // contiguous s_loads
#pragma unroll
      for (int kk = 0; kk < 32; ++kk) {
        const float wv = wr[kk];
        const float4 xv = *(const float4*)&xs[kk * 256 + (l << 2)];
        t[0] = fmaf(xv.x, wv, t[0]);
        t[1] = fmaf(xv.y, wv, t[1]);
        t[2] = fmaf(xv.z, wv, t[2]);
        t[3] = fmaf(xv.w, wv, t[3]);
      }
    }
    const float bv = bias[iu];
#pragma unroll
    for (int q = 0; q < 4; ++q) t[q] += bv;

    const float sb2 = ws[WS_B2S];
    float acc[4];
#pragma unroll
    for (int q = 0; q < 4; ++q) acc[q] = sb2;
    const float* __restrict__ W1row = W1 + iu * HH1;  // uniform -> s_load
    const float2* __restrict__ pr = (const float2*)(ws + WS_PAIR);
#pragma unroll 8
    for (int j = 0; j < HH1; ++j) {
      const float sw1 = W1row[j];
      const float2 p = pr[j];
      const float vb = p.x;
#pragma unroll
      for (int q = 0; q < 4; ++q) {
        const float h = fmaxf(fmaf(t[q], sw1, vb), 0.f);
        acc[q] = fmaf(h, p.y, acc[q]);
      }
    }
#pragma unroll
    for (int q = 0; q < 4; ++q) ts[((l << 2) + q) * 9 + w] = acc[q];
    __syncthreads();
    {
      const int m = tid >> 1, half = tid & 1;
      float4 o;
      o.x = ts[m * 9 + (half << 2) + 0];
      o.y = ts[m * 9 + (half << 2) + 1];
      o.z = ts[m * 9 + (half << 2) + 2];
      o.w = ts[m * 9 + (half << 2) + 3];
      *(float4*)&out[(n0 + m) * DD + i0 + (half << 2)] = o;
    }
  }

  // S3 = S2@S, S4 = S2@S2 on blocks 0..63 (4 rows each)
  if (b < 64) {
    const bool isS4 = b >= 32;
    const int mb = b & 31;
    const float* __restrict__ L = ws + WS_S2;
    const float* __restrict__ R = ws + (isS4 ? WS_S2 : WS_S);
    float* __restrict__ O = ws + (isS4 ? WS_S4 : WS_S3);
    const int i = (mb << 2) + (tid >> 7), j = tid & 127;
    float acc = 0.f;
#pragma unroll 8
    for (int k = 0; k < DD; ++k) acc = fmaf(L[i * DD + k], R[k * DD + j], acc);
    O[i * DD + j] = acc;
  }

  gridBarrier(bar + 1, 256);

  if (b >= 32) return;

  // ================= phase 2: traces + finalize (blocks 0..31) =========
  {
    const int i = (b << 2) + (tid >> 7), j = tid & 127;
    const float* S1 = ws + WS_S;
    const float* S2 = ws + WS_S2;
    const float* S3 = ws + WS_S3;
    const float* S4 = ws + WS_S4;
    const float a1 = S1[i * DD + j], a2 = S2[i * DD + j], a3 = S3[i * DD + j];
    const float b1t = S1[j * DD + i], b2t = S2[j * DD + i],
                b3t = S3[j * DD + i], b4t = S4[j * DD + i];
    float e7 = 0.f;
#pragma unroll 8
    for (int k = 0; k < DD; ++k) e7 = fmaf(S3[i * DD + k], S4[k * DD + j], e7);
    float c[10];
    c[0] = a1 * b1t; c[1] = a2 * b1t; c[2] = a2 * b2t; c[3] = a3 * b2t;
    c[4] = a3 * b3t; c[5] = a3 * b4t; c[6] = e7 * b1t; c[7] = e7 * b2t;
    c[8] = e7 * b3t; c[9] = e7 * b4t;
    float* red = smem;  // [8][10]
#pragma unroll
    for (int m = 0; m < 10; ++m) {
      const float v = waveReduce(c[m]);
      if ((tid & 63) == 0) red[(tid >> 6) * 10 + m] = v;
    }
    __syncthreads();
    if (tid == 0) {
      float* tacc = ws + WS_TACC;
      for (int m = 0; m < 10; ++m) {
        float s = 0.f;
        for (int wv = 0; wv < 8; ++wv) s += red[wv * 10 + m];
        atomicAdd(&tacc[m], s);
      }
      __threadfence();
      unsigned int* done = (unsigned int*)(ws + WS_DONE);
      const unsigned int old = atomicAdd(done, 1u);
      if (old == 31u) {
        __threadfence();
        double h = 0.0, C = 8128.0;  // C(128,2)
        for (int kk = 2; kk <= 11; ++kk) {
          const float tv = atomicAdd(&tacc[kk - 2], 0.0f);
          h += C * (double)tv;
          C = C * (double)(128 - kk) / (double)(kk + 1);
        }
        float reg = 0.f;
        for (int m = 0; m < 8; ++m) reg += ws[WS_REGP + m];
        out[NN * DD] = (float)h;
        out[NN * DD + 1] = reg;
      }
    }
  }
}

// =====================================================================
// OLD PATH (fallback when ws_size is too small)
// =====================================================================
__global__ __launch_bounds__(256) void kA_old(
    const float* __restrict__ weight, const float* __restrict__ Amat,
    const float* __restrict__ W2, const float* __restrict__ b2,
    float* __restrict__ ws) {
  const int b = blockIdx.x, tid = threadIdx.x;
  if (b < 64) {
    __shared__ float s_lds[DD * DD];
    const float4* w4 = (const float4*)weight;
    const float4* a4 = (const float4*)Amat;
    float4* s4 = (float4*)s_lds;
    const float inv = 1.0f / 128.0f;
    for (int e = tid; e < DD * DD / 4; e += 256) {
      float4 wv = w4[e], av = a4[e], o;
      float t;
      t = wv.x * av.x; o.x = t * t * inv;
      t = wv.y * av.y; o.y = t * t * inv;
      t = wv.z * av.z; o.z = t * t * inv;
      t = wv.w * av.w; o.w = t * t * inv;
      s4[e] = o;
    }
    __syncthreads();
    const int i = (b << 1) + (tid >> 7), j = tid & 127;
    const float* row = &s_lds[i * DD];
    float acc = 0.f;
#pragma unroll 8
    for (int k = 0; k < DD; ++k) acc = fmaf(row[k], s_lds[k * DD + j], acc);
    ws[O_S2 + i * DD + j] = acc;
  } else if (b < 72) {
    const int base = (b - 64) * 2048;
    const float inv = 1.0f / 128.0f;
    for (int e = tid; e < 2048; e += 256) {
      const int idx = base + e;
      const float w = weight[idx] * Amat[idx];
      ws[O_S + idx] = w * w * inv;
    }
  } else if (b == 72) {
    const float4* r = (const float4*)(W2 + tid * 128);
    float4 s4 = make_float4(0.f, 0.f, 0.f, 0.f);
#pragma unroll 8
    for (int k = 0; k < 32; ++k) {
      const float4 v = r[k];
      s4.x += v.x; s4.y += v.y; s4.z += v.z; s4.w += v.w;
    }
    ws[O_W2S + tid] = (s4.x + s4.y) + (s4.z + s4.w);
  } else if (b == 73) {
    __shared__ float red[4];
    float v = (tid < 128) ? b2[tid] : 0.f;
    v = waveReduce(v);
    if ((tid & 63) == 0) red[tid >> 6] = v;
    __syncthreads();
    if (tid == 0) ws[O_B2S] = (red[0] + red[1]) + (red[2] + red[3]);
    if (tid >= 64 && tid < 74) ws[O_TACC + (tid - 64)] = 0.f;
    if (tid == 96) *(unsigned int*)(ws + O_DONE) = 0u;
  } else {
    const int bb = b - 74;
    const int base = bb * 2048;
    float s = 0.f;
    for (int e = tid; e < 2048; e += 256) {
      const int idx = base + e;
      s += fabsf(weight[idx] * Amat[idx]);
    }
    s = waveReduce(s);
    __shared__ float red[4];
    if ((tid & 63) == 0) red[tid >> 6] = s;
    __syncthreads();
    if (tid == 0) ws[O_REGP + bb] = (red[0] + red[1]) + (red[2] + red[3]);
  }
}

__global__ __launch_bounds__(256) void kB_old(
    const float* __restrict__ x, const float* __restrict__ weight,
    const float* __restrict__ Amat, const float* __restrict__ bias,
    const float* __restrict__ W1, const float* __restrict__ b1v,
    float* __restrict__ ws, float* __restrict__ out) {
  const int tid = threadIdx.x;
  if (blockIdx.x < 128) {
    const int sb = blockIdx.x;
    const bool isS4 = sb >= 64;
    const int mb = isS4 ? sb - 64 : sb;
    const float* __restrict__ L = ws + O_S2;
    const float* __restrict__ R = ws + (isS4 ? O_S2 : O_S);
    float* __restrict__ O = ws + (isS4 ? O_S4 : O_S3);
    const int i = (mb << 1) + (tid >> 7), j = tid & 127;
    float acc = 0.f;
#pragma unroll 8
    for (int k = 0; k < DD; ++k) acc = fmaf(L[i * DD + k], R[k * DD + j], acc);
    O[i * DD + j] = acc;
    return;
  }
  __shared__ float xs[64 * 132];
  __shared__ float4 fq[4 * 256];
  __shared__ float wcol[4 * 128];
  __shared__ float ts[64 * 5];
  const int fb = blockIdx.x - 128;
  const int i0 = (fb & 31) << 2, n0 = (fb >> 5) << 6;
  const float4* x4 = (const float4*)x;
  for (int e = tid; e < 64 * 32; e += 256) {
    const int r = e >> 5, c = e & 31;
    *(float4*)&xs[r * 132 + (c << 2)] = x4[(n0 + r) * 32 + c];
  }
  for (int e = tid; e < 512; e += 256) {
    const int w = e >> 7, k = e & 127;
    const int gi = k * DD + i0 + w;
    wcol[(w << 7) + k] = weight[gi] * Amat[gi];
  }
  const float* w2s = ws + O_W2S;
  for (int e = tid; e < 1024; e += 256) {
    const int w = e >> 8, j = e & 255;
    fq[(w << 8) + j] = make_float4(W1[(i0 + w) * HH1 + j], b1v[j], w2s[j], 0.f);
  }
  __syncthreads();
  const int w = tid >> 6, l = tid & 63;
  float t = bias[i0 + w];
  const float4* xr = (const float4*)&xs[l * 132];
  const float4* wc = (const float4*)&wcol[w << 7];
#pragma unroll
  for (int k = 0; k < 32; ++k) {
    const float4 xv = xr[k], wv = wc[k];
    t = fmaf(xv.x, wv.x, t);
    t = fmaf(xv.y, wv.y, t);
    t = fmaf(xv.z, wv.z, t);
    t = fmaf(xv.w, wv.w, t);
  }
  float acc = ws[O_B2S];
  const float4* fp = &fq[w << 8];
#pragma unroll 8
  for (int j = 0; j < HH1; ++j) {
    const float4 c = fp[j];
    acc = fmaf(fmaxf(fmaf(t, c.x, c.y), 0.f), c.z, acc);
  }
  ts[l * 5 + w] = acc;
  __syncthreads();
  if (tid < 64) {
    const float4 o = make_float4(ts[tid * 5 + 0], ts[tid * 5 + 1],
                                 ts[tid * 5 + 2], ts[tid * 5 + 3]);
    *(float4*)&out[(n0 + tid) * DD + i0] = o;
  }
}

__global__ __launch_bounds__(256) void kC_old(float* __restrict__ ws,
                                              float* __restrict__ out) {
  const int tid = threadIdx.x;
  const int i = (blockIdx.x << 1) + (tid >> 7), j = tid & 127;
  const float* S1 = ws + O_S;
  const float* S2 = ws + O_S2;
  const float* S3 = ws + O_S3;
  const float* S4 = ws + O_S4;
  const float a1 = S1[i * DD + j], a2 = S2[i * DD + j], a3 = S3[i * DD + j];
  const float b1t = S1[j * DD + i], b2t = S2[j * DD + i],
              b3t = S3[j * DD + i], b4t = S4[j * DD + i];
  float e7 = 0.f;
#pragma unroll 8
  for (int k = 0; k < DD; ++k) e7 = fmaf(S3[i * DD + k], S4[k * DD + j], e7);
  float c[10];
  c[0] = a1 * b1t; c[1] = a2 * b1t; c[2] = a2 * b2t; c[3] = a3 * b2t;
  c[4] = a3 * b3t; c[5] = a3 * b4t; c[6] = e7 * b1t; c[7] = e7 * b2t;
  c[8] = e7 * b3t; c[9] = e7 * b4t;
  __shared__ float red[4][10];
#pragma unroll
  for (int m = 0; m < 10; ++m) {
    const float v = waveReduce(c[m]);
    if ((tid & 63) == 0) red[tid >> 6][m] = v;
  }
  __syncthreads();
  if (tid == 0) {
    float* tacc = ws + O_TACC;
    for (int m = 0; m < 10; ++m)
      atomicAdd(&tacc[m], (red[0][m] + red[1][m]) + (red[2][m] + red[3][m]));
    __threadfence();
    unsigned int* done = (unsigned int*)(ws + O_DONE);
    const unsigned int old = atomicAdd(done, 1u);
    if (old == 63u) {
      __threadfence();
      double h = 0.0, C = 8128.0;
      for (int kk = 2; kk <= 11; ++kk) {
        const float tv = atomicAdd(&tacc[kk - 2], 0.0f);
        h += C * (double)tv;
        C = C * (double)(128 - kk) / (double)(kk + 1);
      }
      float reg = 0.f;
      for (int m = 0; m < 8; ++m) reg += ws[O_REGP + m];
      out[NN * DD] = (float)h;
      out[NN * DD + 1] = reg;
    }
  }
}

extern "C" void kernel_launch(void* const* d_in, const int* in_sizes, int n_in,
                              void* d_out, int out_size, void* d_ws,
                              size_t ws_size, hipStream_t stream) {
  const float* x      = (const float*)d_in[0];
  const float* weight = (const float*)d_in[1];
  const float* bias   = (const float*)d_in[2];
  const float* Amat   = (const float*)d_in[3];
  const float* W1     = (const float*)d_in[4];
  const float* b1v    = (const float*)d_in[5];
  const float* W2     = (const float*)d_in[6];
  const float* b2     = (const float*)d_in[7];
  float* out = (float*)d_out;
  float* ws  = (float*)d_ws;

  if (ws_size >= WS_REQ_BYTES) {
    // zero the grid-barrier slots (ws is poisoned each iteration)
    hipMemsetAsync((char*)d_ws + WS_BAR * 4UL, 0, 16, stream);
    kFused<<<256, 512, 0, stream>>>(x, weight, Amat, bias, W1, b1v, W2, b2,
                                    ws, out);
  } else {
    kA_old<<<82, 256, 0, stream>>>(weight, Amat, W2, b2, ws);
    kB_old<<<128 + 2048, 256, 0, stream>>>(x, weight, Amat, bias, W1, b1v, ws,
                                           out);
    kC_old<<<64, 256, 0, stream>>>(ws, out);
  }
}

// Round 3
// 125.782 us; speedup vs baseline: 1.5755x; 1.5755x over previous
//
#include <hip/hip_runtime.h>

#define NN 4096
#define DD 128
#define HH1 256

// ---------------- new-path workspace float offsets ----------------
#define WS_S    0        // 16384 : S = (weight*A)^2 / 128
#define WS_S2   16384    // 16384
#define WS_S3   32768    // 16384
#define WS_S4   49152    // 16384
#define WS_W    65536    // 16384 : W = weight*A
#define WS_W2S  81920    // 256
#define WS_PAIR 82176    // 512   : float2 {b1[j], w2s[j]}
#define WS_B2S  82688    // 1
#define WS_TACC 82696    // 10
#define WS_DONE 82708    // 1 (uint)
#define WS_REGP 82712    // 8
#define WS_XT   82944    // 524288 : xT[128][4096]
#define WS_REQ_FLOATS 607232
#define WS_REQ_BYTES  (WS_REQ_FLOATS * 4UL)

// ---------------- old-path (fallback) offsets ----------------
#define O_S    0
#define O_S2   16384
#define O_S3   32768
#define O_S4   49152
#define O_W2S  65536
#define O_B2S  65792
#define O_TACC 65808
#define O_DONE 65824
#define O_REGP 65840

__device__ __forceinline__ float waveReduce(float v) {
#pragma unroll
  for (int off = 32; off > 0; off >>= 1) v += __shfl_down(v, off, 64);
  return v;
}

// =====================================================================
// NEW PATH (3 kernels, no grid barriers — round-0 structure, ky fused
// into kf via consecutive-n float4 reads of xT)
// =====================================================================

// kA2: 0..63 S^2 | 64..71 S & W | 72 w2s+pair | 73 b2s+zero | 74..81 reg
//      82..113 xT transpose   (verbatim from the 109.6us round-0 kernel)
__global__ __launch_bounds__(256) void kA2(
    const float* __restrict__ weight, const float* __restrict__ Amat,
    const float* __restrict__ W2, const float* __restrict__ b2,
    const float* __restrict__ b1v, const float* __restrict__ x,
    float* __restrict__ ws) {
  const int b = blockIdx.x, tid = threadIdx.x;
  __shared__ float s_lds[DD * DD];   // 64 KB (S^2 blocks)
  __shared__ float xs[128 * 133];    // 68 KB (transpose blocks)
  if (b < 64) {
    const float4* w4 = (const float4*)weight;
    const float4* a4 = (const float4*)Amat;
    float4* s4 = (float4*)s_lds;
    const float inv = 1.0f / 128.0f;
    for (int e = tid; e < DD * DD / 4; e += 256) {
      float4 wv = w4[e], av = a4[e], o;
      float t;
      t = wv.x * av.x; o.x = t * t * inv;
      t = wv.y * av.y; o.y = t * t * inv;
      t = wv.z * av.z; o.z = t * t * inv;
      t = wv.w * av.w; o.w = t * t * inv;
      s4[e] = o;
    }
    __syncthreads();
    const int i = (b << 1) + (tid >> 7), j = tid & 127;
    const float* row = &s_lds[i * DD];
    float acc = 0.f;
#pragma unroll 8
    for (int k = 0; k < DD; ++k) acc = fmaf(row[k], s_lds[k * DD + j], acc);
    ws[WS_S2 + i * DD + j] = acc;
  } else if (b < 72) {
    const int base = (b - 64) * 2048;
    const float inv = 1.0f / 128.0f;
    for (int e = tid; e < 2048; e += 256) {
      const int idx = base + e;
      const float w = weight[idx] * Amat[idx];
      ws[WS_W + idx] = w;
      ws[WS_S + idx] = w * w * inv;
    }
  } else if (b == 72) {
    const float4* r = (const float4*)(W2 + tid * 128);
    float4 s4 = make_float4(0.f, 0.f, 0.f, 0.f);
#pragma unroll 8
    for (int k = 0; k < 32; ++k) {
      const float4 v = r[k];
      s4.x += v.x; s4.y += v.y; s4.z += v.z; s4.w += v.w;
    }
    const float w2sv = (s4.x + s4.y) + (s4.z + s4.w);
    ws[WS_W2S + tid] = w2sv;
    ((float2*)(ws + WS_PAIR))[tid] = make_float2(b1v[tid], w2sv);
  } else if (b == 73) {
    __shared__ float red[4];
    float v = (tid < 128) ? b2[tid] : 0.f;
    v = waveReduce(v);
    if ((tid & 63) == 0) red[tid >> 6] = v;
    __syncthreads();
    if (tid == 0) ws[WS_B2S] = (red[0] + red[1]) + (red[2] + red[3]);
    if (tid >= 64 && tid < 74) ws[WS_TACC + (tid - 64)] = 0.f;
    if (tid == 96) *(unsigned int*)(ws + WS_DONE) = 0u;
  } else if (b < 82) {
    const int bb = b - 74;
    const int base = bb * 2048;
    float s = 0.f;
    for (int e = tid; e < 2048; e += 256) {
      const int idx = base + e;
      s += fabsf(weight[idx] * Amat[idx]);
    }
    s = waveReduce(s);
    __shared__ float red2[4];
    if ((tid & 63) == 0) red2[tid >> 6] = s;
    __syncthreads();
    if (tid == 0) ws[WS_REGP + bb] = (red2[0] + red2[1]) + (red2[2] + red2[3]);
  } else {
    // xT transpose: 32 blocks, 128-row tiles
    const int n0 = (b - 82) * 128;
    const float4* x4 = (const float4*)x;
    for (int e = tid; e < 4096; e += 256) {
      const int r = e >> 5, c = e & 31;
      const float4 v = x4[(n0 + r) * 32 + c];
      float* p = &xs[r * 133 + (c << 2)];
      p[0] = v.x; p[1] = v.y; p[2] = v.z; p[3] = v.w;
    }
    __syncthreads();
    float* xT = ws + WS_XT;
    const int c = tid & 31, ks = tid >> 5;
#pragma unroll 4
    for (int m = 0; m < 16; ++m) {
      const int k = ks + (m << 3);
      float4 o;
      o.x = xs[((c << 2) + 0) * 133 + k];
      o.y = xs[((c << 2) + 1) * 133 + k];
      o.z = xs[((c << 2) + 2) * 133 + k];
      o.w = xs[((c << 2) + 3) * 133 + k];
      *(float4*)&xT[k * NN + n0 + (c << 2)] = o;
    }
  }
}

// kS34: 128 blocks — S3 = S2@S (0..63), S4 = S2@S2 (64..127), 2 rows/block
__global__ __launch_bounds__(256) void kS34(float* __restrict__ ws) {
  const int tid = threadIdx.x;
  const int sb = blockIdx.x;
  const bool isS4 = sb >= 64;
  const int mb = isS4 ? sb - 64 : sb;
  const float* __restrict__ L = ws + WS_S2;
  const float* __restrict__ R = ws + (isS4 ? WS_S2 : WS_S);
  float* __restrict__ O = ws + (isS4 ? WS_S4 : WS_S3);
  const int i = (mb << 1) + (tid >> 7), j = tid & 127;
  float acc = 0.f;
#pragma unroll 8
  for (int k = 0; k < DD; ++k) acc = fmaf(L[i * DD + k], R[k * DD + j], acc);
  O[i * DD + j] = acc;
}

// kC4: 0..511 fused y+MLP collapse (each block: 256 n x 4 i, y computed
//      in-register from xT with one coalesced float4/k) | 512..575 traces
__global__ __launch_bounds__(256) void kC4(const float* __restrict__ W1,
                                           const float* __restrict__ bias,
                                           float* __restrict__ ws,
                                           float* __restrict__ out) {
  const int tid = threadIdx.x;
  if (blockIdx.x < 512) {
    __shared__ float ts[256 * 5];
    const int fb = blockIdx.x;
    const int n0 = (fb >> 5) << 8, i0 = (fb & 31) << 2;  // 256 n x 4 i
    const int w = tid >> 6, l = tid & 63;
    const int iu = __builtin_amdgcn_readfirstlane(i0 + w);  // force SGPR
    const float* __restrict__ xT = ws + WS_XT;
    const float* __restrict__ Wm = ws + WS_W;

    // y[n0+4l+q][iu]: one coalesced float4 xT read + one s_load W per k
    float t[4] = {0.f, 0.f, 0.f, 0.f};
#pragma unroll 8
    for (int k = 0; k < DD; ++k) {
      const float wv = Wm[k * DD + iu];  // uniform -> s_load
      const float4 xv = *(const float4*)&xT[k * NN + n0 + (l << 2)];
      t[0] = fmaf(xv.x, wv, t[0]);
      t[1] = fmaf(xv.y, wv, t[1]);
      t[2] = fmaf(xv.z, wv, t[2]);
      t[3] = fmaf(xv.w, wv, t[3]);
    }
    const float bv = bias[iu];
#pragma unroll
    for (int q = 0; q < 4; ++q) t[q] += bv;

    // MLP collapse (inner loop identical to the verified round-0 kC2)
    const float sb2 = ws[WS_B2S];
    float acc[4];
#pragma unroll
    for (int q = 0; q < 4; ++q) acc[q] = sb2;
    const float* __restrict__ W1row = W1 + iu * HH1;  // uniform -> s_load
    const float2* __restrict__ pr = (const float2*)(ws + WS_PAIR);
#pragma unroll 8
    for (int j = 0; j < HH1; ++j) {
      const float sw1 = W1row[j];      // s_load
      const float2 p = pr[j];          // s_load_dwordx2
      const float vb = p.x;
#pragma unroll
      for (int q = 0; q < 4; ++q) {
        const float h = fmaxf(fmaf(t[q], sw1, vb), 0.f);
        acc[q] = fmaf(h, p.y, acc[q]);
      }
    }
#pragma unroll
    for (int q = 0; q < 4; ++q) ts[((l << 2) + q) * 5 + w] = acc[q];
    __syncthreads();
    const int m = tid;  // 256 rows
    float4 o;
    o.x = ts[m * 5 + 0]; o.y = ts[m * 5 + 1];
    o.z = ts[m * 5 + 2]; o.w = ts[m * 5 + 3];
    *(float4*)&out[(n0 + m) * DD + i0] = o;
    return;
  }
  // ---- trace blocks ----
  const int tb = blockIdx.x - 512;
  const int i = (tb << 1) + (tid >> 7), j = tid & 127;
  const float* S1 = ws + WS_S;
  const float* S2 = ws + WS_S2;
  const float* S3 = ws + WS_S3;
  const float* S4 = ws + WS_S4;
  const float a1 = S1[i * DD + j], a2 = S2[i * DD + j], a3 = S3[i * DD + j];
  const float b1t = S1[j * DD + i], b2t = S2[j * DD + i],
              b3t = S3[j * DD + i], b4t = S4[j * DD + i];
  float e7 = 0.f;
#pragma unroll 8
  for (int k = 0; k < DD; ++k) e7 = fmaf(S3[i * DD + k], S4[k * DD + j], e7);
  float c[10];
  c[0] = a1 * b1t; c[1] = a2 * b1t; c[2] = a2 * b2t; c[3] = a3 * b2t;
  c[4] = a3 * b3t; c[5] = a3 * b4t; c[6] = e7 * b1t; c[7] = e7 * b2t;
  c[8] = e7 * b3t; c[9] = e7 * b4t;
  __shared__ float red[4][10];
#pragma unroll
  for (int m = 0; m < 10; ++m) {
    const float v = waveReduce(c[m]);
    if ((tid & 63) == 0) red[tid >> 6][m] = v;
  }
  __syncthreads();
  if (tid == 0) {
    float* tacc = ws + WS_TACC;
    for (int m = 0; m < 10; ++m)
      atomicAdd(&tacc[m], (red[0][m] + red[1][m]) + (red[2][m] + red[3][m]));
    __threadfence();
    unsigned int* done = (unsigned int*)(ws + WS_DONE);
    const unsigned int old = atomicAdd(done, 1u);
    if (old == 63u) {
      __threadfence();
      double h = 0.0, C = 8128.0;  // C(128,2)
      for (int kk = 2; kk <= 11; ++kk) {
        const float tv = atomicAdd(&tacc[kk - 2], 0.0f);
        h += C * (double)tv;
        C = C * (double)(128 - kk) / (double)(kk + 1);
      }
      float reg = 0.f;
      for (int m = 0; m < 8; ++m) reg += ws[WS_REGP + m];
      out[NN * DD] = (float)h;
      out[NN * DD + 1] = reg;
    }
  }
}

// =====================================================================
// OLD PATH (fallback when ws_size is too small)
// =====================================================================
__global__ __launch_bounds__(256) void kA_old(
    const float* __restrict__ weight, const float* __restrict__ Amat,
    const float* __restrict__ W2, const float* __restrict__ b2,
    float* __restrict__ ws) {
  const int b = blockIdx.x, tid = threadIdx.x;
  if (b < 64) {
    __shared__ float s_lds[DD * DD];
    const float4* w4 = (const float4*)weight;
    const float4* a4 = (const float4*)Amat;
    float4* s4 = (float4*)s_lds;
    const float inv = 1.0f / 128.0f;
    for (int e = tid; e < DD * DD / 4; e += 256) {
      float4 wv = w4[e], av = a4[e], o;
      float t;
      t = wv.x * av.x; o.x = t * t * inv;
      t = wv.y * av.y; o.y = t * t * inv;
      t = wv.z * av.z; o.z = t * t * inv;
      t = wv.w * av.w; o.w = t * t * inv;
      s4[e] = o;
    }
    __syncthreads();
    const int i = (b << 1) + (tid >> 7), j = tid & 127;
    const float* row = &s_lds[i * DD];
    float acc = 0.f;
#pragma unroll 8
    for (int k = 0; k < DD; ++k) acc = fmaf(row[k], s_lds[k * DD + j], acc);
    ws[O_S2 + i * DD + j] = acc;
  } else if (b < 72) {
    const int base = (b - 64) * 2048;
    const float inv = 1.0f / 128.0f;
    for (int e = tid; e < 2048; e += 256) {
      const int idx = base + e;
      const float w = weight[idx] * Amat[idx];
      ws[O_S + idx] = w * w * inv;
    }
  } else if (b == 72) {
    const float4* r = (const float4*)(W2 + tid * 128);
    float4 s4 = make_float4(0.f, 0.f, 0.f, 0.f);
#pragma unroll 8
    for (int k = 0; k < 32; ++k) {
      const float4 v = r[k];
      s4.x += v.x; s4.y += v.y; s4.z += v.z; s4.w += v.w;
    }
    ws[O_W2S + tid] = (s4.x + s4.y) + (s4.z + s4.w);
  } else if (b == 73) {
    __shared__ float red[4];
    float v = (tid < 128) ? b2[tid] : 0.f;
    v = waveReduce(v);
    if ((tid & 63) == 0) red[tid >> 6] = v;
    __syncthreads();
    if (tid == 0) ws[O_B2S] = (red[0] + red[1]) + (red[2] + red[3]);
    if (tid >= 64 && tid < 74) ws[O_TACC + (tid - 64)] = 0.f;
    if (tid == 96) *(unsigned int*)(ws + O_DONE) = 0u;
  } else {
    const int bb = b - 74;
    const int base = bb * 2048;
    float s = 0.f;
    for (int e = tid; e < 2048; e += 256) {
      const int idx = base + e;
      s += fabsf(weight[idx] * Amat[idx]);
    }
    s = waveReduce(s);
    __shared__ float red[4];
    if ((tid & 63) == 0) red[tid >> 6] = s;
    __syncthreads();
    if (tid == 0) ws[O_REGP + bb] = (red[0] + red[1]) + (red[2] + red[3]);
  }
}

__global__ __launch_bounds__(256) void kB_old(
    const float* __restrict__ x, const float* __restrict__ weight,
    const float* __restrict__ Amat, const float* __restrict__ bias,
    const float* __restrict__ W1, const float* __restrict__ b1v,
    float* __restrict__ ws, float* __restrict__ out) {
  const int tid = threadIdx.x;
  if (blockIdx.x < 128) {
    const int sb = blockIdx.x;
    const bool isS4 = sb >= 64;
    const int mb = isS4 ? sb - 64 : sb;
    const float* __restrict__ L = ws + O_S2;
    const float* __restrict__ R = ws + (isS4 ? O_S2 : O_S);
    float* __restrict__ O = ws + (isS4 ? O_S4 : O_S3);
    const int i = (mb << 1) + (tid >> 7), j = tid & 127;
    float acc = 0.f;
#pragma unroll 8
    for (int k = 0; k < DD; ++k) acc = fmaf(L[i * DD + k], R[k * DD + j], acc);
    O[i * DD + j] = acc;
    return;
  }
  __shared__ float xs[64 * 132];
  __shared__ float4 fq[4 * 256];
  __shared__ float wcol[4 * 128];
  __shared__ float ts[64 * 5];
  const int fb = blockIdx.x - 128;
  const int i0 = (fb & 31) << 2, n0 = (fb >> 5) << 6;
  const float4* x4 = (const float4*)x;
  for (int e = tid; e < 64 * 32; e += 256) {
    const int r = e >> 5, c = e & 31;
    *(float4*)&xs[r * 132 + (c << 2)] = x4[(n0 + r) * 32 + c];
  }
  for (int e = tid; e < 512; e += 256) {
    const int w = e >> 7, k = e & 127;
    const int gi = k * DD + i0 + w;
    wcol[(w << 7) + k] = weight[gi] * Amat[gi];
  }
  const float* w2s = ws + O_W2S;
  for (int e = tid; e < 1024; e += 256) {
    const int w = e >> 8, j = e & 255;
    fq[(w << 8) + j] = make_float4(W1[(i0 + w) * HH1 + j], b1v[j], w2s[j], 0.f);
  }
  __syncthreads();
  const int w = tid >> 6, l = tid & 63;
  float t = bias[i0 + w];
  const float4* xr = (const float4*)&xs[l * 132];
  const float4* wc = (const float4*)&wcol[w << 7];
#pragma unroll
  for (int k = 0; k < 32; ++k) {
    const float4 xv = xr[k], wv = wc[k];
    t = fmaf(xv.x, wv.x, t);
    t = fmaf(xv.y, wv.y, t);
    t = fmaf(xv.z, wv.z, t);
    t = fmaf(xv.w, wv.w, t);
  }
  float acc = ws[O_B2S];
  const float4* fp = &fq[w << 8];
#pragma unroll 8
  for (int j = 0; j < HH1; ++j) {
    const float4 c = fp[j];
    acc = fmaf(fmaxf(fmaf(t, c.x, c.y), 0.f), c.z, acc);
  }
  ts[l * 5 + w] = acc;
  __syncthreads();
  if (tid < 64) {
    const float4 o = make_float4(ts[tid * 5 + 0], ts[tid * 5 + 1],
                                 ts[tid * 5 + 2], ts[tid * 5 + 3]);
    *(float4*)&out[(n0 + tid) * DD + i0] = o;
  }
}

__global__ __launch_bounds__(256) void kC_old(float* __restrict__ ws,
                                              float* __restrict__ out) {
  const int tid = threadIdx.x;
  const int i = (blockIdx.x << 1) + (tid >> 7), j = tid & 127;
  const float* S1 = ws + O_S;
  const float* S2 = ws + O_S2;
  const float* S3 = ws + O_S3;
  const float* S4 = ws + O_S4;
  const float a1 = S1[i * DD + j], a2 = S2[i * DD + j], a3 = S3[i * DD + j];
  const float b1t = S1[j * DD + i], b2t = S2[j * DD + i],
              b3t = S3[j * DD + i], b4t = S4[j * DD + i];
  float e7 = 0.f;
#pragma unroll 8
  for (int k = 0; k < DD; ++k) e7 = fmaf(S3[i * DD + k], S4[k * DD + j], e7);
  float c[10];
  c[0] = a1 * b1t; c[1] = a2 * b1t; c[2] = a2 * b2t; c[3] = a3 * b2t;
  c[4] = a3 * b3t; c[5] = a3 * b4t; c[6] = e7 * b1t; c[7] = e7 * b2t;
  c[8] = e7 * b3t; c[9] = e7 * b4t;
  __shared__ float red[4][10];
#pragma unroll
  for (int m = 0; m < 10; ++m) {
    const float v = waveReduce(c[m]);
    if ((tid & 63) == 0) red[tid >> 6][m] = v;
  }
  __syncthreads();
  if (tid == 0) {
    float* tacc = ws + O_TACC;
    for (int m = 0; m < 10; ++m)
      atomicAdd(&tacc[m], (red[0][m] + red[1][m]) + (red[2][m] + red[3][m]));
    __threadfence();
    unsigned int* done = (unsigned int*)(ws + O_DONE);
    const unsigned int old = atomicAdd(done, 1u);
    if (old == 63u) {
      __threadfence();
      double h = 0.0, C = 8128.0;
      for (int kk = 2; kk <= 11; ++kk) {
        const float tv = atomicAdd(&tacc[kk - 2], 0.0f);
        h += C * (double)tv;
        C = C * (double)(128 - kk) / (double)(kk + 1);
      }
      float reg = 0.f;
      for (int m = 0; m < 8; ++m) reg += ws[O_REGP + m];
      out[NN * DD] = (float)h;
      out[NN * DD + 1] = reg;
    }
  }
}

extern "C" void kernel_launch(void* const* d_in, const int* in_sizes, int n_in,
                              void* d_out, int out_size, void* d_ws,
                              size_t ws_size, hipStream_t stream) {
  const float* x      = (const float*)d_in[0];
  const float* weight = (const float*)d_in[1];
  const float* bias   = (const float*)d_in[2];
  const float* Amat   = (const float*)d_in[3];
  const float* W1     = (const float*)d_in[4];
  const float* b1v    = (const float*)d_in[5];
  const float* W2     = (const float*)d_in[6];
  const float* b2     = (const float*)d_in[7];
  float* out = (float*)d_out;
  float* ws  = (float*)d_ws;

  if (ws_size >= WS_REQ_BYTES) {
    kA2<<<114, 256, 0, stream>>>(weight, Amat, W2, b2, b1v, x, ws);
    kS34<<<128, 256, 0, stream>>>(ws);
    kC4<<<576, 256, 0, stream>>>(W1, bias, ws, out);
  } else {
    kA_old<<<82, 256, 0, stream>>>(weight, Amat, W2, b2, ws);
    kB_old<<<128 + 2048, 256, 0, stream>>>(x, weight, Amat, bias, W1, b1v, ws,
                                           out);
    kC_old<<<64, 256, 0, stream>>>(ws, out);
  }
}

// Round 4
// 125.459 us; speedup vs baseline: 1.5795x; 1.0026x over previous
//
#include <hip/hip_runtime.h>

#define NN 4096
#define DD 128
#define HH1 256

// ---------------- new-path workspace float offsets ----------------
#define WS_S    0        // 16384 : S = (weight*A)^2 / 128
#define WS_S2   16384    // 16384
#define WS_S3   32768    // 16384
#define WS_S4   49152    // 16384
#define WS_W    65536    // 16384 : W = weight*A
#define WS_W2S  81920    // 256
#define WS_PAIR 82176    // 512   : float2 {b1[j], w2s[j]}
#define WS_B2S  82688    // 1
#define WS_TACC 82696    // 10
#define WS_DONE 82708    // 1 (uint)
#define WS_REGP 82712    // 8
#define WS_WT   82944    // 16384 : WT[i][k] = W[k][i]
#define WS_XT   99328    // 524288 : xT[128][4096]
#define WS_REQ_FLOATS 623616
#define WS_REQ_BYTES  (WS_REQ_FLOATS * 4UL)

// ---------------- old-path (fallback) offsets ----------------
#define O_S    0
#define O_S2   16384
#define O_S3   32768
#define O_S4   49152
#define O_W2S  65536
#define O_B2S  65792
#define O_TACC 65808
#define O_DONE 65824
#define O_REGP 65840

__device__ __forceinline__ float waveReduce(float v) {
#pragma unroll
  for (int off = 32; off > 0; off >>= 1) v += __shfl_down(v, off, 64);
  return v;
}

// =====================================================================
// NEW PATH (3 kernels)
// =====================================================================

// kA2: 0..63 S^2 | 64..71 W/WT/S | 72 w2s+pair | 73 b2s+zero | 74..81 reg
//      82..145 xT transpose (64-row tiles, 2x wider than before)
__global__ __launch_bounds__(256) void kA2(
    const float* __restrict__ weight, const float* __restrict__ Amat,
    const float* __restrict__ W2, const float* __restrict__ b2,
    const float* __restrict__ b1v, const float* __restrict__ x,
    float* __restrict__ ws) {
  const int b = blockIdx.x, tid = threadIdx.x;
  __shared__ float s_lds[DD * DD];   // 64 KB (S^2 blocks)
  __shared__ float xs[64 * 133];     // 34 KB (transpose blocks)
  if (b < 64) {
    const float4* w4 = (const float4*)weight;
    const float4* a4 = (const float4*)Amat;
    float4* s4 = (float4*)s_lds;
    const float inv = 1.0f / 128.0f;
    for (int e = tid; e < DD * DD / 4; e += 256) {
      float4 wv = w4[e], av = a4[e], o;
      float t;
      t = wv.x * av.x; o.x = t * t * inv;
      t = wv.y * av.y; o.y = t * t * inv;
      t = wv.z * av.z; o.z = t * t * inv;
      t = wv.w * av.w; o.w = t * t * inv;
      s4[e] = o;
    }
    __syncthreads();
    const int i = (b << 1) + (tid >> 7), j = tid & 127;
    const float* row = &s_lds[i * DD];
    float acc = 0.f;
#pragma unroll 8
    for (int k = 0; k < DD; ++k) acc = fmaf(row[k], s_lds[k * DD + j], acc);
    ws[WS_S2 + i * DD + j] = acc;
  } else if (b < 72) {
    const int base = (b - 64) * 2048;
    const float inv = 1.0f / 128.0f;
    for (int e = tid; e < 2048; e += 256) {
      const int idx = base + e;
      const float w = weight[idx] * Amat[idx];
      const int k = idx >> 7, i = idx & 127;
      ws[WS_W + idx] = w;
      ws[WS_WT + i * DD + k] = w;   // transposed copy for kC5 s_load stream
      ws[WS_S + idx] = w * w * inv;
    }
  } else if (b == 72) {
    const float4* r = (const float4*)(W2 + tid * 128);
    float4 s4 = make_float4(0.f, 0.f, 0.f, 0.f);
#pragma unroll 8
    for (int k = 0; k < 32; ++k) {
      const float4 v = r[k];
      s4.x += v.x; s4.y += v.y; s4.z += v.z; s4.w += v.w;
    }
    const float w2sv = (s4.x + s4.y) + (s4.z + s4.w);
    ws[WS_W2S + tid] = w2sv;
    ((float2*)(ws + WS_PAIR))[tid] = make_float2(b1v[tid], w2sv);
  } else if (b == 73) {
    __shared__ float red[4];
    float v = (tid < 128) ? b2[tid] : 0.f;
    v = waveReduce(v);
    if ((tid & 63) == 0) red[tid >> 6] = v;
    __syncthreads();
    if (tid == 0) ws[WS_B2S] = (red[0] + red[1]) + (red[2] + red[3]);
    if (tid >= 64 && tid < 74) ws[WS_TACC + (tid - 64)] = 0.f;
    if (tid == 96) *(unsigned int*)(ws + WS_DONE) = 0u;
  } else if (b < 82) {
    const int bb = b - 74;
    const int base = bb * 2048;
    float s = 0.f;
    for (int e = tid; e < 2048; e += 256) {
      const int idx = base + e;
      s += fabsf(weight[idx] * Amat[idx]);
    }
    s = waveReduce(s);
    __shared__ float red2[4];
    if ((tid & 63) == 0) red2[tid >> 6] = s;
    __syncthreads();
    if (tid == 0) ws[WS_REGP + bb] = (red2[0] + red2[1]) + (red2[2] + red2[3]);
  } else {
    // xT transpose: 64 blocks, 64-row tiles
    const int n0 = (b - 82) * 64;
    const float4* x4 = (const float4*)x;
    for (int e = tid; e < 2048; e += 256) {
      const int r = e >> 5, c = e & 31;
      const float4 v = x4[(n0 + r) * 32 + c];
      float* p = &xs[r * 133 + (c << 2)];
      p[0] = v.x; p[1] = v.y; p[2] = v.z; p[3] = v.w;
    }
    __syncthreads();
    float* xT = ws + WS_XT;
    const int c = tid & 15, ks = tid >> 4;  // c: 16 float4 cols, ks: 0..15
#pragma unroll
    for (int m = 0; m < 8; ++m) {
      const int k = ks + (m << 4);
      float4 o;
      o.x = xs[((c << 2) + 0) * 133 + k];
      o.y = xs[((c << 2) + 1) * 133 + k];
      o.z = xs[((c << 2) + 2) * 133 + k];
      o.w = xs[((c << 2) + 3) * 133 + k];
      *(float4*)&xT[k * NN + n0 + (c << 2)] = o;
    }
  }
}

// kS34: 128 blocks — S3 = S2@S (0..63), S4 = S2@S2 (64..127), 2 rows/block
__global__ __launch_bounds__(256) void kS34(float* __restrict__ ws) {
  const int tid = threadIdx.x;
  const int sb = blockIdx.x;
  const bool isS4 = sb >= 64;
  const int mb = isS4 ? sb - 64 : sb;
  const float* __restrict__ L = ws + WS_S2;
  const float* __restrict__ R = ws + (isS4 ? WS_S2 : WS_S);
  float* __restrict__ O = ws + (isS4 ? WS_S4 : WS_S3);
  const int i = (mb << 1) + (tid >> 7), j = tid & 127;
  float acc = 0.f;
#pragma unroll 8
  for (int k = 0; k < DD; ++k) acc = fmaf(L[i * DD + k], R[k * DD + j], acc);
  O[i * DD + j] = acc;
}

// kC5: 0..1023 fused y+MLP collapse (each block: 128 n x 4 i, 2 n/thread
//      -> 4096 waves for occupancy; WT gives contiguous s_load stream)
//      | 1024..1087 traces
__global__ __launch_bounds__(256) void kC5(const float* __restrict__ W1,
                                           const float* __restrict__ bias,
                                           float* __restrict__ ws,
                                           float* __restrict__ out) {
  const int tid = threadIdx.x;
  if (blockIdx.x < 1024) {
    __shared__ float ts[128 * 5];
    const int fb = blockIdx.x;
    const int n0 = (fb >> 5) << 7, i0 = (fb & 31) << 2;  // 128 n x 4 i
    const int w = tid >> 6, l = tid & 63;
    const int iu = __builtin_amdgcn_readfirstlane(i0 + w);  // force SGPR
    const float* __restrict__ xT = ws + WS_XT;
    const float* __restrict__ wr = ws + WS_WT + iu * DD;  // contiguous s_load

    // y[n0+2l+q][iu]: one coalesced float2 + one contiguous s_load per k
    float t0 = 0.f, t1 = 0.f;
#pragma unroll 8
    for (int k = 0; k < DD; ++k) {
      const float wv = wr[k];
      const float2 xv = *(const float2*)&xT[k * NN + n0 + (l << 1)];
      t0 = fmaf(xv.x, wv, t0);
      t1 = fmaf(xv.y, wv, t1);
    }
    const float bv = bias[iu];
    t0 += bv;
    t1 += bv;

    // MLP collapse
    const float sb2 = ws[WS_B2S];
    float a0 = sb2, a1 = sb2;
    const float* __restrict__ W1row = W1 + iu * HH1;  // uniform -> s_load
    const float2* __restrict__ pr = (const float2*)(ws + WS_PAIR);
#pragma unroll 8
    for (int j = 0; j < HH1; ++j) {
      const float sw1 = W1row[j];      // s_load
      const float2 p = pr[j];          // s_load_dwordx2
      const float h0 = fmaxf(fmaf(t0, sw1, p.x), 0.f);
      const float h1 = fmaxf(fmaf(t1, sw1, p.x), 0.f);
      a0 = fmaf(h0, p.y, a0);
      a1 = fmaf(h1, p.y, a1);
    }
    ts[((l << 1) + 0) * 5 + w] = a0;
    ts[((l << 1) + 1) * 5 + w] = a1;
    __syncthreads();
    if (tid < 128) {
      const int m = tid;
      float4 o;
      o.x = ts[m * 5 + 0]; o.y = ts[m * 5 + 1];
      o.z = ts[m * 5 + 2]; o.w = ts[m * 5 + 3];
      *(float4*)&out[(n0 + m) * DD + i0] = o;
    }
    return;
  }
  // ---- trace blocks ----
  const int tb = blockIdx.x - 1024;
  const int i = (tb << 1) + (tid >> 7), j = tid & 127;
  const float* S1 = ws + WS_S;
  const float* S2 = ws + WS_S2;
  const float* S3 = ws + WS_S3;
  const float* S4 = ws + WS_S4;
  const float a1 = S1[i * DD + j], a2 = S2[i * DD + j], a3 = S3[i * DD + j];
  const float b1t = S1[j * DD + i], b2t = S2[j * DD + i],
              b3t = S3[j * DD + i], b4t = S4[j * DD + i];
  float e7 = 0.f;
#pragma unroll 8
  for (int k = 0; k < DD; ++k) e7 = fmaf(S3[i * DD + k], S4[k * DD + j], e7);
  float c[10];
  c[0] = a1 * b1t; c[1] = a2 * b1t; c[2] = a2 * b2t; c[3] = a3 * b2t;
  c[4] = a3 * b3t; c[5] = a3 * b4t; c[6] = e7 * b1t; c[7] = e7 * b2t;
  c[8] = e7 * b3t; c[9] = e7 * b4t;
  __shared__ float red[4][10];
#pragma unroll
  for (int m = 0; m < 10; ++m) {
    const float v = waveReduce(c[m]);
    if ((tid & 63) == 0) red[tid >> 6][m] = v;
  }
  __syncthreads();
  if (tid == 0) {
    float* tacc = ws + WS_TACC;
    for (int m = 0; m < 10; ++m)
      atomicAdd(&tacc[m], (red[0][m] + red[1][m]) + (red[2][m] + red[3][m]));
    __threadfence();
    unsigned int* done = (unsigned int*)(ws + WS_DONE);
    const unsigned int old = atomicAdd(done, 1u);
    if (old == 63u) {
      __threadfence();
      double h = 0.0, C = 8128.0;  // C(128,2)
      for (int kk = 2; kk <= 11; ++kk) {
        const float tv = atomicAdd(&tacc[kk - 2], 0.0f);
        h += C * (double)tv;
        C = C * (double)(128 - kk) / (double)(kk + 1);
      }
      float reg = 0.f;
      for (int m = 0; m < 8; ++m) reg += ws[WS_REGP + m];
      out[NN * DD] = (float)h;
      out[NN * DD + 1] = reg;
    }
  }
}

// =====================================================================
// OLD PATH (fallback when ws_size is too small)
// =====================================================================
__global__ __launch_bounds__(256) void kA_old(
    const float* __restrict__ weight, const float* __restrict__ Amat,
    const float* __restrict__ W2, const float* __restrict__ b2,
    float* __restrict__ ws) {
  const int b = blockIdx.x, tid = threadIdx.x;
  if (b < 64) {
    __shared__ float s_lds[DD * DD];
    const float4* w4 = (const float4*)weight;
    const float4* a4 = (const float4*)Amat;
    float4* s4 = (float4*)s_lds;
    const float inv = 1.0f / 128.0f;
    for (int e = tid; e < DD * DD / 4; e += 256) {
      float4 wv = w4[e], av = a4[e], o;
      float t;
      t = wv.x * av.x; o.x = t * t * inv;
      t = wv.y * av.y; o.y = t * t * inv;
      t = wv.z * av.z; o.z = t * t * inv;
      t = wv.w * av.w; o.w = t * t * inv;
      s4[e] = o;
    }
    __syncthreads();
    const int i = (b << 1) + (tid >> 7), j = tid & 127;
    const float* row = &s_lds[i * DD];
    float acc = 0.f;
#pragma unroll 8
    for (int k = 0; k < DD; ++k) acc = fmaf(row[k], s_lds[k * DD + j], acc);
    ws[O_S2 + i * DD + j] = acc;
  } else if (b < 72) {
    const int base = (b - 64) * 2048;
    const float inv = 1.0f / 128.0f;
    for (int e = tid; e < 2048; e += 256) {
      const int idx = base + e;
      const float w = weight[idx] * Amat[idx];
      ws[O_S + idx] = w * w * inv;
    }
  } else if (b == 72) {
    const float4* r = (const float4*)(W2 + tid * 128);
    float4 s4 = make_float4(0.f, 0.f, 0.f, 0.f);
#pragma unroll 8
    for (int k = 0; k < 32; ++k) {
      const float4 v = r[k];
      s4.x += v.x; s4.y += v.y; s4.z += v.z; s4.w += v.w;
    }
    ws[O_W2S + tid] = (s4.x + s4.y) + (s4.z + s4.w);
  } else if (b == 73) {
    __shared__ float red[4];
    float v = (tid < 128) ? b2[tid] : 0.f;
    v = waveReduce(v);
    if ((tid & 63) == 0) red[tid >> 6] = v;
    __syncthreads();
    if (tid == 0) ws[O_B2S] = (red[0] + red[1]) + (red[2] + red[3]);
    if (tid >= 64 && tid < 74) ws[O_TACC + (tid - 64)] = 0.f;
    if (tid == 96) *(unsigned int*)(ws + O_DONE) = 0u;
  } else {
    const int bb = b - 74;
    const int base = bb * 2048;
    float s = 0.f;
    for (int e = tid; e < 2048; e += 256) {
      const int idx = base + e;
      s += fabsf(weight[idx] * Amat[idx]);
    }
    s = waveReduce(s);
    __shared__ float red[4];
    if ((tid & 63) == 0) red[tid >> 6] = s;
    __syncthreads();
    if (tid == 0) ws[O_REGP + bb] = (red[0] + red[1]) + (red[2] + red[3]);
  }
}

__global__ __launch_bounds__(256) void kB_old(
    const float* __restrict__ x, const float* __restrict__ weight,
    const float* __restrict__ Amat, const float* __restrict__ bias,
    const float* __restrict__ W1, const float* __restrict__ b1v,
    float* __restrict__ ws, float* __restrict__ out) {
  const int tid = threadIdx.x;
  if (blockIdx.x < 128) {
    const int sb = blockIdx.x;
    const bool isS4 = sb >= 64;
    const int mb = isS4 ? sb - 64 : sb;
    const float* __restrict__ L = ws + O_S2;
    const float* __restrict__ R = ws + (isS4 ? O_S2 : O_S);
    float* __restrict__ O = ws + (isS4 ? O_S4 : O_S3);
    const int i = (mb << 1) + (tid >> 7), j = tid & 127;
    float acc = 0.f;
#pragma unroll 8
    for (int k = 0; k < DD; ++k) acc = fmaf(L[i * DD + k], R[k * DD + j], acc);
    O[i * DD + j] = acc;
    return;
  }
  __shared__ float xs[64 * 132];
  __shared__ float4 fq[4 * 256];
  __shared__ float wcol[4 * 128];
  __shared__ float ts[64 * 5];
  const int fb = blockIdx.x - 128;
  const int i0 = (fb & 31) << 2, n0 = (fb >> 5) << 6;
  const float4* x4 = (const float4*)x;
  for (int e = tid; e < 64 * 32; e += 256) {
    const int r = e >> 5, c = e & 31;
    *(float4*)&xs[r * 132 + (c << 2)] = x4[(n0 + r) * 32 + c];
  }
  for (int e = tid; e < 512; e += 256) {
    const int w = e >> 7, k = e & 127;
    const int gi = k * DD + i0 + w;
    wcol[(w << 7) + k] = weight[gi] * Amat[gi];
  }
  const float* w2s = ws + O_W2S;
  for (int e = tid; e < 1024; e += 256) {
    const int w = e >> 8, j = e & 255;
    fq[(w << 8) + j] = make_float4(W1[(i0 + w) * HH1 + j], b1v[j], w2s[j], 0.f);
  }
  __syncthreads();
  const int w = tid >> 6, l = tid & 63;
  float t = bias[i0 + w];
  const float4* xr = (const float4*)&xs[l * 132];
  const float4* wc = (const float4*)&wcol[w << 7];
#pragma unroll
  for (int k = 0; k < 32; ++k) {
    const float4 xv = xr[k], wv = wc[k];
    t = fmaf(xv.x, wv.x, t);
    t = fmaf(xv.y, wv.y, t);
    t = fmaf(xv.z, wv.z, t);
    t = fmaf(xv.w, wv.w, t);
  }
  float acc = ws[O_B2S];
  const float4* fp = &fq[w << 8];
#pragma unroll 8
  for (int j = 0; j < HH1; ++j) {
    const float4 c = fp[j];
    acc = fmaf(fmaxf(fmaf(t, c.x, c.y), 0.f), c.z, acc);
  }
  ts[l * 5 + w] = acc;
  __syncthreads();
  if (tid < 64) {
    const float4 o = make_float4(ts[tid * 5 + 0], ts[tid * 5 + 1],
                                 ts[tid * 5 + 2], ts[tid * 5 + 3]);
    *(float4*)&out[(n0 + tid) * DD + i0] = o;
  }
}

__global__ __launch_bounds__(256) void kC_old(float* __restrict__ ws,
                                              float* __restrict__ out) {
  const int tid = threadIdx.x;
  const int i = (blockIdx.x << 1) + (tid >> 7), j = tid & 127;
  const float* S1 = ws + O_S;
  const float* S2 = ws + O_S2;
  const float* S3 = ws + O_S3;
  const float* S4 = ws + O_S4;
  const float a1 = S1[i * DD + j], a2 = S2[i * DD + j], a3 = S3[i * DD + j];
  const float b1t = S1[j * DD + i], b2t = S2[j * DD + i],
              b3t = S3[j * DD + i], b4t = S4[j * DD + i];
  float e7 = 0.f;
#pragma unroll 8
  for (int k = 0; k < DD; ++k) e7 = fmaf(S3[i * DD + k], S4[k * DD + j], e7);
  float c[10];
  c[0] = a1 * b1t; c[1] = a2 * b1t; c[2] = a2 * b2t; c[3] = a3 * b2t;
  c[4] = a3 * b3t; c[5] = a3 * b4t; c[6] = e7 * b1t; c[7] = e7 * b2t;
  c[8] = e7 * b3t; c[9] = e7 * b4t;
  __shared__ float red[4][10];
#pragma unroll
  for (int m = 0; m < 10; ++m) {
    const float v = waveReduce(c[m]);
    if ((tid & 63) == 0) red[tid >> 6][m] = v;
  }
  __syncthreads();
  if (tid == 0) {
    float* tacc = ws + O_TACC;
    for (int m = 0; m < 10; ++m)
      atomicAdd(&tacc[m], (red[0][m] + red[1][m]) + (red[2][m] + red[3][m]));
    __threadfence();
    unsigned int* done = (unsigned int*)(ws + O_DONE);
    const unsigned int old = atomicAdd(done, 1u);
    if (old == 63u) {
      __threadfence();
      double h = 0.0, C = 8128.0;
      for (int kk = 2; kk <= 11; ++kk) {
        const float tv = atomicAdd(&tacc[kk - 2], 0.0f);
        h += C * (double)tv;
        C = C * (double)(128 - kk) / (double)(kk + 1);
      }
      float reg = 0.f;
      for (int m = 0; m < 8; ++m) reg += ws[O_REGP + m];
      out[NN * DD] = (float)h;
      out[NN * DD + 1] = reg;
    }
  }
}

extern "C" void kernel_launch(void* const* d_in, const int* in_sizes, int n_in,
                              void* d_out, int out_size, void* d_ws,
                              size_t ws_size, hipStream_t stream) {
  const float* x      = (const float*)d_in[0];
  const float* weight = (const float*)d_in[1];
  const float* bias   = (const float*)d_in[2];
  const float* Amat   = (const float*)d_in[3];
  const float* W1     = (const float*)d_in[4];
  const float* b1v    = (const float*)d_in[5];
  const float* W2     = (const float*)d_in[6];
  const float* b2     = (const float*)d_in[7];
  float* out = (float*)d_out;
  float* ws  = (float*)d_ws;

  if (ws_size >= WS_REQ_BYTES) {
    kA2<<<146, 256, 0, stream>>>(weight, Amat, W2, b2, b1v, x, ws);
    kS34<<<128, 256, 0, stream>>>(ws);
    kC5<<<1088, 256, 0, stream>>>(W1, bias, ws, out);
  } else {
    kA_old<<<82, 256, 0, stream>>>(weight, Amat, W2, b2, ws);
    kB_old<<<128 + 2048, 256, 0, stream>>>(x, weight, Amat, bias, W1, b1v, ws,
                                           out);
    kC_old<<<64, 256, 0, stream>>>(ws, out);
  }
}

// Round 5
// 116.456 us; speedup vs baseline: 1.7016x; 1.0773x over previous
//
#include <hip/hip_runtime.h>

#define NN 4096
#define DD 128
#define HH1 256

// ---------------- new-path workspace float offsets ----------------
#define WS_S    0        // 16384 : S = (weight*A)^2 / 128
#define WS_S2   16384    // 16384
#define WS_S3   32768    // 16384
#define WS_S4   49152    // 16384
#define WS_W    65536    // 16384 : W = weight*A
#define WS_W2S  81920    // 256
#define WS_PAIR 82176    // 512   : float2 {b1[j], w2s[j]}
#define WS_B2S  82688    // 1
#define WS_TACC 82696    // 10
#define WS_DONE 82708    // 1 (uint)
#define WS_REGP 82712    // 8
#define WS_WT   82944    // 16384 : WT[i][k] = W[k][i]
#define WS_XT   99328    // 524288 : xT[128][4096]
#define WS_TH   623616   // 32768 : sorted thresholds  T[i][256]
#define WS_A    656384   // 32896 : segment slopes     A[i][257]
#define WS_B    689280   // 32896 : segment intercepts B[i][257]
#define WS_REQ_FLOATS 722176
#define WS_REQ_BYTES  (WS_REQ_FLOATS * 4UL)

// ---------------- old-path (fallback) offsets ----------------
#define O_S    0
#define O_S2   16384
#define O_S3   32768
#define O_S4   49152
#define O_W2S  65536
#define O_B2S  65792
#define O_TACC 65808
#define O_DONE 65824
#define O_REGP 65840

__device__ __forceinline__ float waveReduce(float v) {
#pragma unroll
  for (int off = 32; off > 0; off >>= 1) v += __shfl_down(v, off, 64);
  return v;
}

// =====================================================================
// NEW PATH (3 kernels)
// =====================================================================

// kA2: 0..63 S^2 | 64..71 W/WT/S | 72 w2s+pair | 73 b2s+zero | 74..81 reg
//      82..145 xT transpose (64-row tiles)
__global__ __launch_bounds__(256) void kA2(
    const float* __restrict__ weight, const float* __restrict__ Amat,
    const float* __restrict__ W2, const float* __restrict__ b2,
    const float* __restrict__ b1v, const float* __restrict__ x,
    float* __restrict__ ws) {
  const int b = blockIdx.x, tid = threadIdx.x;
  __shared__ float s_lds[DD * DD];   // 64 KB (S^2 blocks)
  __shared__ float xs[64 * 133];     // 34 KB (transpose blocks)
  if (b < 64) {
    const float4* w4 = (const float4*)weight;
    const float4* a4 = (const float4*)Amat;
    float4* s4 = (float4*)s_lds;
    const float inv = 1.0f / 128.0f;
    for (int e = tid; e < DD * DD / 4; e += 256) {
      float4 wv = w4[e], av = a4[e], o;
      float t;
      t = wv.x * av.x; o.x = t * t * inv;
      t = wv.y * av.y; o.y = t * t * inv;
      t = wv.z * av.z; o.z = t * t * inv;
      t = wv.w * av.w; o.w = t * t * inv;
      s4[e] = o;
    }
    __syncthreads();
    const int i = (b << 1) + (tid >> 7), j = tid & 127;
    const float* row = &s_lds[i * DD];
    float acc = 0.f;
#pragma unroll 8
    for (int k = 0; k < DD; ++k) acc = fmaf(row[k], s_lds[k * DD + j], acc);
    ws[WS_S2 + i * DD + j] = acc;
  } else if (b < 72) {
    const int base = (b - 64) * 2048;
    const float inv = 1.0f / 128.0f;
    for (int e = tid; e < 2048; e += 256) {
      const int idx = base + e;
      const float w = weight[idx] * Amat[idx];
      const int k = idx >> 7, i = idx & 127;
      ws[WS_W + idx] = w;
      ws[WS_WT + i * DD + k] = w;   // transposed copy for kC6 s_load stream
      ws[WS_S + idx] = w * w * inv;
    }
  } else if (b == 72) {
    const float4* r = (const float4*)(W2 + tid * 128);
    float4 s4 = make_float4(0.f, 0.f, 0.f, 0.f);
#pragma unroll 8
    for (int k = 0; k < 32; ++k) {
      const float4 v = r[k];
      s4.x += v.x; s4.y += v.y; s4.z += v.z; s4.w += v.w;
    }
    const float w2sv = (s4.x + s4.y) + (s4.z + s4.w);
    ws[WS_W2S + tid] = w2sv;
    ((float2*)(ws + WS_PAIR))[tid] = make_float2(b1v[tid], w2sv);
  } else if (b == 73) {
    __shared__ float red[4];
    float v = (tid < 128) ? b2[tid] : 0.f;
    v = waveReduce(v);
    if ((tid & 63) == 0) red[tid >> 6] = v;
    __syncthreads();
    if (tid == 0) ws[WS_B2S] = (red[0] + red[1]) + (red[2] + red[3]);
    if (tid >= 64 && tid < 74) ws[WS_TACC + (tid - 64)] = 0.f;
    if (tid == 96) *(unsigned int*)(ws + WS_DONE) = 0u;
  } else if (b < 82) {
    const int bb = b - 74;
    const int base = bb * 2048;
    float s = 0.f;
    for (int e = tid; e < 2048; e += 256) {
      const int idx = base + e;
      s += fabsf(weight[idx] * Amat[idx]);
    }
    s = waveReduce(s);
    __shared__ float red2[4];
    if ((tid & 63) == 0) red2[tid >> 6] = s;
    __syncthreads();
    if (tid == 0) ws[WS_REGP + bb] = (red2[0] + red2[1]) + (red2[2] + red2[3]);
  } else {
    // xT transpose: 64 blocks, 64-row tiles
    const int n0 = (b - 82) * 64;
    const float4* x4 = (const float4*)x;
    for (int e = tid; e < 2048; e += 256) {
      const int r = e >> 5, c = e & 31;
      const float4 v = x4[(n0 + r) * 32 + c];
      float* p = &xs[r * 133 + (c << 2)];
      p[0] = v.x; p[1] = v.y; p[2] = v.z; p[3] = v.w;
    }
    __syncthreads();
    float* xT = ws + WS_XT;
    const int c = tid & 15, ks = tid >> 4;  // c: 16 float4 cols, ks: 0..15
#pragma unroll
    for (int m = 0; m < 8; ++m) {
      const int k = ks + (m << 4);
      float4 o;
      o.x = xs[((c << 2) + 0) * 133 + k];
      o.y = xs[((c << 2) + 1) * 133 + k];
      o.z = xs[((c << 2) + 2) * 133 + k];
      o.w = xs[((c << 2) + 3) * 133 + k];
      *(float4*)&xT[k * NN + n0 + (c << 2)] = o;
    }
  }
}

// kPS: 0..127 S3/S4 matmuls | 128..255 piecewise-linear table build (per i)
__global__ __launch_bounds__(256) void kPS(const float* __restrict__ W1,
                                           const float* __restrict__ b1v,
                                           float* __restrict__ ws) {
  const int tid = threadIdx.x;
  if (blockIdx.x < 128) {
    const int sb = blockIdx.x;
    const bool isS4 = sb >= 64;
    const int mb = isS4 ? sb - 64 : sb;
    const float* __restrict__ L = ws + WS_S2;
    const float* __restrict__ R = ws + (isS4 ? WS_S2 : WS_S);
    float* __restrict__ O = ws + (isS4 ? WS_S4 : WS_S3);
    const int i = (mb << 1) + (tid >> 7), j = tid & 127;
    float acc = 0.f;
#pragma unroll 8
    for (int k = 0; k < DD; ++k) acc = fmaf(L[i * DD + k], R[k * DD + j], acc);
    O[i * DD + j] = acc;
    return;
  }
  // ---- piecewise-linear table for row i ----
  const int i = blockIdx.x - 128;
  __shared__ float kT[256], kS[256], kC[256];
  __shared__ float redb[8];
  __shared__ float base2[2];
  const int j = tid;
  const float w = W1[i * HH1 + j];
  const float w2s = ws[WS_W2S + j];
  const float bj = b1v[j];
  const float s = w * w2s, c = bj * w2s;
  float th, ds, dc, bs, bc;
  if (w > 0.f) {
    th = -bj / w; ds = s; dc = c; bs = 0.f; bc = 0.f;
  } else if (w < 0.f) {
    th = -bj / w; ds = -s; dc = -c; bs = s; bc = c;
  } else {
    th = 3.4e38f; ds = 0.f; dc = 0.f; bs = 0.f; bc = fmaxf(bj, 0.f) * w2s;
  }
  // base (y -> -inf): all negative-w terms active + constants
  {
    const float rs = waveReduce(bs), rc = waveReduce(bc);
    if ((tid & 63) == 0) {
      redb[tid >> 6] = rs;
      redb[4 + (tid >> 6)] = rc;
    }
  }
  kT[tid] = th; kS[tid] = ds; kC[tid] = dc;
  __syncthreads();
  if (tid == 0) {
    base2[0] = (redb[0] + redb[1]) + (redb[2] + redb[3]);
    base2[1] = (redb[4] + redb[5]) + (redb[6] + redb[7]);
  }
  // bitonic sort ascending by th, payload (ds, dc)
  for (int kk = 2; kk <= 256; kk <<= 1) {
    for (int jj = kk >> 1; jj > 0; jj >>= 1) {
      __syncthreads();
      const int ixj = tid ^ jj;
      if (ixj > tid) {
        const bool up = ((tid & kk) == 0);
        const float ta = kT[tid], tb = kT[ixj];
        if ((ta > tb) == up) {
          kT[tid] = tb; kT[ixj] = ta;
          const float sa = kS[tid], sb = kS[ixj];
          kS[tid] = sb; kS[ixj] = sa;
          const float ca = kC[tid], cb = kC[ixj];
          kC[tid] = cb; kC[ixj] = ca;
        }
      }
    }
  }
  __syncthreads();
  // inclusive Hillis-Steele scan of (ds, dc)
  for (int off = 1; off < 256; off <<= 1) {
    float vs = 0.f, vc = 0.f;
    if (tid >= off) { vs = kS[tid - off]; vc = kC[tid - off]; }
    __syncthreads();
    kS[tid] += vs; kC[tid] += vc;
    __syncthreads();
  }
  const float b_s = base2[0], b_c = base2[1];
  ws[WS_TH + i * 256 + tid] = kT[tid];
  ws[WS_A + i * 257 + tid + 1] = b_s + kS[tid];
  ws[WS_B + i * 257 + tid + 1] = b_c + kC[tid];
  if (tid == 0) {
    ws[WS_A + i * 257] = b_s;
    ws[WS_B + i * 257] = b_c;
  }
}

// kC6: 0..511 fused y + piecewise-linear f (256 n x 4 i per block)
//      | 512..575 traces
__global__ __launch_bounds__(256) void kC6(const float* __restrict__ bias,
                                           float* __restrict__ ws,
                                           float* __restrict__ out) {
  const int tid = threadIdx.x;
  if (blockIdx.x < 512) {
    __shared__ float lT[4 * 256];
    __shared__ float lA[4 * 257];
    __shared__ float lB[4 * 257];
    __shared__ float ts[256 * 5];
    const int fb = blockIdx.x;
    const int n0 = (fb >> 5) << 8, i0 = (fb & 31) << 2;  // 256 n x 4 i
    const int w = tid >> 6, l = tid & 63;
    const int iu = __builtin_amdgcn_readfirstlane(i0 + w);  // force SGPR

    // stage tables for the block's 4 i-rows
#pragma unroll
    for (int q = 0; q < 4; ++q) {
      lT[(q << 8) + tid] = ws[WS_TH + (i0 + q) * 256 + tid];
      lA[q * 257 + tid] = ws[WS_A + (i0 + q) * 257 + tid];
      lB[q * 257 + tid] = ws[WS_B + (i0 + q) * 257 + tid];
      if (tid == 0) {
        lA[q * 257 + 256] = ws[WS_A + (i0 + q) * 257 + 256];
        lB[q * 257 + 256] = ws[WS_B + (i0 + q) * 257 + 256];
      }
    }

    // y[n0+4l+q][iu]: coalesced float4 xT read + contiguous WT s_load per k
    const float* __restrict__ xT = ws + WS_XT;
    const float* __restrict__ wr = ws + WS_WT + iu * DD;
    float t[4] = {0.f, 0.f, 0.f, 0.f};
#pragma unroll 8
    for (int k = 0; k < DD; ++k) {
      const float wv = wr[k];
      const float4 xv = *(const float4*)&xT[k * NN + n0 + (l << 2)];
      t[0] = fmaf(xv.x, wv, t[0]);
      t[1] = fmaf(xv.y, wv, t[1]);
      t[2] = fmaf(xv.z, wv, t[2]);
      t[3] = fmaf(xv.w, wv, t[3]);
    }
    const float bv = bias[iu];
    const float sb2 = ws[WS_B2S];
    __syncthreads();  // tables staged

    const float* Tw = &lT[w << 8];
    const float* Aw = &lA[w * 257];
    const float* Bw = &lB[w * 257];
#pragma unroll
    for (int q = 0; q < 4; ++q) {
      const float yq = t[q] + bv;
      int m = 0;
#pragma unroll
      for (int st = 128; st > 0; st >>= 1) {
        if (Tw[m + st - 1] <= yq) m += st;
      }
      const float f = fmaf(Aw[m], yq, Bw[m]) + sb2;
      ts[((l << 2) + q) * 5 + w] = f;
    }
    __syncthreads();
    const int m = tid;  // 256 rows
    float4 o;
    o.x = ts[m * 5 + 0]; o.y = ts[m * 5 + 1];
    o.z = ts[m * 5 + 2]; o.w = ts[m * 5 + 3];
    *(float4*)&out[(n0 + m) * DD + i0] = o;
    return;
  }
  // ---- trace blocks ----
  const int tb = blockIdx.x - 512;
  const int i = (tb << 1) + (tid >> 7), j = tid & 127;
  const float* S1 = ws + WS_S;
  const float* S2 = ws + WS_S2;
  const float* S3 = ws + WS_S3;
  const float* S4 = ws + WS_S4;
  const float a1 = S1[i * DD + j], a2 = S2[i * DD + j], a3 = S3[i * DD + j];
  const float b1t = S1[j * DD + i], b2t = S2[j * DD + i],
              b3t = S3[j * DD + i], b4t = S4[j * DD + i];
  float e7 = 0.f;
#pragma unroll 8
  for (int k = 0; k < DD; ++k) e7 = fmaf(S3[i * DD + k], S4[k * DD + j], e7);
  float c[10];
  c[0] = a1 * b1t; c[1] = a2 * b1t; c[2] = a2 * b2t; c[3] = a3 * b2t;
  c[4] = a3 * b3t; c[5] = a3 * b4t; c[6] = e7 * b1t; c[7] = e7 * b2t;
  c[8] = e7 * b3t; c[9] = e7 * b4t;
  __shared__ float red[4][10];
#pragma unroll
  for (int m = 0; m < 10; ++m) {
    const float v = waveReduce(c[m]);
    if ((tid & 63) == 0) red[tid >> 6][m] = v;
  }
  __syncthreads();
  if (tid == 0) {
    float* tacc = ws + WS_TACC;
    for (int m = 0; m < 10; ++m)
      atomicAdd(&tacc[m], (red[0][m] + red[1][m]) + (red[2][m] + red[3][m]));
    __threadfence();
    unsigned int* done = (unsigned int*)(ws + WS_DONE);
    const unsigned int old = atomicAdd(done, 1u);
    if (old == 63u) {
      __threadfence();
      double h = 0.0, C = 8128.0;  // C(128,2)
      for (int kk = 2; kk <= 11; ++kk) {
        const float tv = atomicAdd(&tacc[kk - 2], 0.0f);
        h += C * (double)tv;
        C = C * (double)(128 - kk) / (double)(kk + 1);
      }
      float reg = 0.f;
      for (int m = 0; m < 8; ++m) reg += ws[WS_REGP + m];
      out[NN * DD] = (float)h;
      out[NN * DD + 1] = reg;
    }
  }
}

// =====================================================================
// OLD PATH (fallback when ws_size is too small)
// =====================================================================
__global__ __launch_bounds__(256) void kA_old(
    const float* __restrict__ weight, const float* __restrict__ Amat,
    const float* __restrict__ W2, const float* __restrict__ b2,
    float* __restrict__ ws) {
  const int b = blockIdx.x, tid = threadIdx.x;
  if (b < 64) {
    __shared__ float s_lds[DD * DD];
    const float4* w4 = (const float4*)weight;
    const float4* a4 = (const float4*)Amat;
    float4* s4 = (float4*)s_lds;
    const float inv = 1.0f / 128.0f;
    for (int e = tid; e < DD * DD / 4; e += 256) {
      float4 wv = w4[e], av = a4[e], o;
      float t;
      t = wv.x * av.x; o.x = t * t * inv;
      t = wv.y * av.y; o.y = t * t * inv;
      t = wv.z * av.z; o.z = t * t * inv;
      t = wv.w * av.w; o.w = t * t * inv;
      s4[e] = o;
    }
    __syncthreads();
    const int i = (b << 1) + (tid >> 7), j = tid & 127;
    const float* row = &s_lds[i * DD];
    float acc = 0.f;
#pragma unroll 8
    for (int k = 0; k < DD; ++k) acc = fmaf(row[k], s_lds[k * DD + j], acc);
    ws[O_S2 + i * DD + j] = acc;
  } else if (b < 72) {
    const int base = (b - 64) * 2048;
    const float inv = 1.0f / 128.0f;
    for (int e = tid; e < 2048; e += 256) {
      const int idx = base + e;
      const float w = weight[idx] * Amat[idx];
      ws[O_S + idx] = w * w * inv;
    }
  } else if (b == 72) {
    const float4* r = (const float4*)(W2 + tid * 128);
    float4 s4 = make_float4(0.f, 0.f, 0.f, 0.f);
#pragma unroll 8
    for (int k = 0; k < 32; ++k) {
      const float4 v = r[k];
      s4.x += v.x; s4.y += v.y; s4.z += v.z; s4.w += v.w;
    }
    ws[O_W2S + tid] = (s4.x + s4.y) + (s4.z + s4.w);
  } else if (b == 73) {
    __shared__ float red[4];
    float v = (tid < 128) ? b2[tid] : 0.f;
    v = waveReduce(v);
    if ((tid & 63) == 0) red[tid >> 6] = v;
    __syncthreads();
    if (tid == 0) ws[O_B2S] = (red[0] + red[1]) + (red[2] + red[3]);
    if (tid >= 64 && tid < 74) ws[O_TACC + (tid - 64)] = 0.f;
    if (tid == 96) *(unsigned int*)(ws + O_DONE) = 0u;
  } else {
    const int bb = b - 74;
    const int base = bb * 2048;
    float s = 0.f;
    for (int e = tid; e < 2048; e += 256) {
      const int idx = base + e;
      s += fabsf(weight[idx] * Amat[idx]);
    }
    s = waveReduce(s);
    __shared__ float red[4];
    if ((tid & 63) == 0) red[tid >> 6] = s;
    __syncthreads();
    if (tid == 0) ws[O_REGP + bb] = (red[0] + red[1]) + (red[2] + red[3]);
  }
}

__global__ __launch_bounds__(256) void kB_old(
    const float* __restrict__ x, const float* __restrict__ weight,
    const float* __restrict__ Amat, const float* __restrict__ bias,
    const float* __restrict__ W1, const float* __restrict__ b1v,
    float* __restrict__ ws, float* __restrict__ out) {
  const int tid = threadIdx.x;
  if (blockIdx.x < 128) {
    const int sb = blockIdx.x;
    const bool isS4 = sb >= 64;
    const int mb = isS4 ? sb - 64 : sb;
    const float* __restrict__ L = ws + O_S2;
    const float* __restrict__ R = ws + (isS4 ? O_S2 : O_S);
    float* __restrict__ O = ws + (isS4 ? O_S4 : O_S3);
    const int i = (mb << 1) + (tid >> 7), j = tid & 127;
    float acc = 0.f;
#pragma unroll 8
    for (int k = 0; k < DD; ++k) acc = fmaf(L[i * DD + k], R[k * DD + j], acc);
    O[i * DD + j] = acc;
    return;
  }
  __shared__ float xs[64 * 132];
  __shared__ float4 fq[4 * 256];
  __shared__ float wcol[4 * 128];
  __shared__ float ts[64 * 5];
  const int fb = blockIdx.x - 128;
  const int i0 = (fb & 31) << 2, n0 = (fb >> 5) << 6;
  const float4* x4 = (const float4*)x;
  for (int e = tid; e < 64 * 32; e += 256) {
    const int r = e >> 5, c = e & 31;
    *(float4*)&xs[r * 132 + (c << 2)] = x4[(n0 + r) * 32 + c];
  }
  for (int e = tid; e < 512; e += 256) {
    const int w = e >> 7, k = e & 127;
    const int gi = k * DD + i0 + w;
    wcol[(w << 7) + k] = weight[gi] * Amat[gi];
  }
  const float* w2s = ws + O_W2S;
  for (int e = tid; e < 1024; e += 256) {
    const int w = e >> 8, j = e & 255;
    fq[(w << 8) + j] = make_float4(W1[(i0 + w) * HH1 + j], b1v[j], w2s[j], 0.f);
  }
  __syncthreads();
  const int w = tid >> 6, l = tid & 63;
  float t = bias[i0 + w];
  const float4* xr = (const float4*)&xs[l * 132];
  const float4* wc = (const float4*)&wcol[w << 7];
#pragma unroll
  for (int k = 0; k < 32; ++k) {
    const float4 xv = xr[k], wv = wc[k];
    t = fmaf(xv.x, wv.x, t);
    t = fmaf(xv.y, wv.y, t);
    t = fmaf(xv.z, wv.z, t);
    t = fmaf(xv.w, wv.w, t);
  }
  float acc = ws[O_B2S];
  const float4* fp = &fq[w << 8];
#pragma unroll 8
  for (int j = 0; j < HH1; ++j) {
    const float4 c = fp[j];
    acc = fmaf(fmaxf(fmaf(t, c.x, c.y), 0.f), c.z, acc);
  }
  ts[l * 5 + w] = acc;
  __syncthreads();
  if (tid < 64) {
    const float4 o = make_float4(ts[tid * 5 + 0], ts[tid * 5 + 1],
                                 ts[tid * 5 + 2], ts[tid * 5 + 3]);
    *(float4*)&out[(n0 + tid) * DD + i0] = o;
  }
}

__global__ __launch_bounds__(256) void kC_old(float* __restrict__ ws,
                                              float* __restrict__ out) {
  const int tid = threadIdx.x;
  const int i = (blockIdx.x << 1) + (tid >> 7), j = tid & 127;
  const float* S1 = ws + O_S;
  const float* S2 = ws + O_S2;
  const float* S3 = ws + O_S3;
  const float* S4 = ws + O_S4;
  const float a1 = S1[i * DD + j], a2 = S2[i * DD + j], a3 = S3[i * DD + j];
  const float b1t = S1[j * DD + i], b2t = S2[j * DD + i],
              b3t = S3[j * DD + i], b4t = S4[j * DD + i];
  float e7 = 0.f;
#pragma unroll 8
  for (int k = 0; k < DD; ++k) e7 = fmaf(S3[i * DD + k], S4[k * DD + j], e7);
  float c[10];
  c[0] = a1 * b1t; c[1] = a2 * b1t; c[2] = a2 * b2t; c[3] = a3 * b2t;
  c[4] = a3 * b3t; c[5] = a3 * b4t; c[6] = e7 * b1t; c[7] = e7 * b2t;
  c[8] = e7 * b3t; c[9] = e7 * b4t;
  __shared__ float red[4][10];
#pragma unroll
  for (int m = 0; m < 10; ++m) {
    const float v = waveReduce(c[m]);
    if ((tid & 63) == 0) red[tid >> 6][m] = v;
  }
  __syncthreads();
  if (tid == 0) {
    float* tacc = ws + O_TACC;
    for (int m = 0; m < 10; ++m)
      atomicAdd(&tacc[m], (red[0][m] + red[1][m]) + (red[2][m] + red[3][m]));
    __threadfence();
    unsigned int* done = (unsigned int*)(ws + O_DONE);
    const unsigned int old = atomicAdd(done, 1u);
    if (old == 63u) {
      __threadfence();
      double h = 0.0, C = 8128.0;
      for (int kk = 2; kk <= 11; ++kk) {
        const float tv = atomicAdd(&tacc[kk - 2], 0.0f);
        h += C * (double)tv;
        C = C * (double)(128 - kk) / (double)(kk + 1);
      }
      float reg = 0.f;
      for (int m = 0; m < 8; ++m) reg += ws[O_REGP + m];
      out[NN * DD] = (float)h;
      out[NN * DD + 1] = reg;
    }
  }
}

extern "C" void kernel_launch(void* const* d_in, const int* in_sizes, int n_in,
                              void* d_out, int out_size, void* d_ws,
                              size_t ws_size, hipStream_t stream) {
  const float* x      = (const float*)d_in[0];
  const float* weight = (const float*)d_in[1];
  const float* bias   = (const float*)d_in[2];
  const float* Amat   = (const float*)d_in[3];
  const float* W1     = (const float*)d_in[4];
  const float* b1v    = (const float*)d_in[5];
  const float* W2     = (const float*)d_in[6];
  const float* b2     = (const float*)d_in[7];
  float* out = (float*)d_out;
  float* ws  = (float*)d_ws;

  if (ws_size >= WS_REQ_BYTES) {
    kA2<<<146, 256, 0, stream>>>(weight, Amat, W2, b2, b1v, x, ws);
    kPS<<<256, 256, 0, stream>>>(W1, b1v, ws);
    kC6<<<576, 256, 0, stream>>>(bias, ws, out);
  } else {
    kA_old<<<82, 256, 0, stream>>>(weight, Amat, W2, b2, ws);
    kB_old<<<128 + 2048, 256, 0, stream>>>(x, weight, Amat, bias, W1, b1v, ws,
                                           out);
    kC_old<<<64, 256, 0, stream>>>(ws, out);
  }
}